// Round 7
// baseline (26.612 us; speedup 1.0000x reference)
//
#include <hip/hip_runtime.h>
#include <math.h>

#define HDIM 1024
#define BATCH 8
#define SEQ 4096
#define NBLK 1024
#define TAG 0x51CAFE77u

// d_ws layout: u32 flags[NBLK] | f32 wpart[4096] | i32 dotp[4][8][1024]
// All cross-block data moves via relaxed agent-scope (sc1) atomics -> L3 is the
// coherence point; no acquire/release cache-maintenance ops anywhere.

__global__ __launch_bounds__(256) void k_all(const float* __restrict__ hs,
                                             const float* __restrict__ W,
                                             const float* __restrict__ bias,
                                             const float* __restrict__ alpha,
                                             float* __restrict__ out,
                                             unsigned int* __restrict__ flags,
                                             float* __restrict__ wpart,
                                             int* __restrict__ dotp) {
    const int tid = threadIdx.x;
    const int wave = tid >> 6, lane = tid & 63;
    const int gw = blockIdx.x * 4 + wave;   // 0..4095
    const int o = gw & (HDIM - 1);          // output row
    const int part = gw >> 10;              // quarter of H
    const int h0 = part * 256 + lane * 4;

    // ---------------- producer: exact sign-dot + |W| partial ----------------
    float4 wv = *reinterpret_cast<const float4*>(W + (size_t)o * HDIM + h0);
    const float we[4] = {wv.x, wv.y, wv.z, wv.w};
    float xe[BATCH][4];
    #pragma unroll
    for (int b = 0; b < BATCH; ++b) {
        float4 xv = *reinterpret_cast<const float4*>(hs + (size_t)b * SEQ * HDIM + h0);
        xe[b][0] = xv.x; xe[b][1] = xv.y; xe[b][2] = xv.z; xe[b][3] = xv.w;
    }

    float aabs = 0.f;
    int n[BATCH], d[BATCH];
    #pragma unroll
    for (int b = 0; b < BATCH; ++b) { n[b] = 0; d[b] = 0; }
    #pragma unroll
    for (int j = 0; j < 4; ++j) {
        unsigned long long wsg = __ballot(we[j] < 0.f);
        unsigned long long wnz = __ballot(we[j] != 0.f);
        aabs += fabsf(we[j]);
        #pragma unroll
        for (int b = 0; b < BATCH; ++b) {
            unsigned long long u = wnz & __ballot(xe[b][j] != 0.f);
            unsigned long long m = (wsg ^ __ballot(xe[b][j] < 0.f)) & u;
            n[b] += __popcll(u);
            d[b] += __popcll(m);
        }
    }
    #pragma unroll
    for (int off = 32; off >= 1; off >>= 1) aabs += __shfl_down(aabs, off, 64);

    if (lane == 0) {
        __hip_atomic_store(&wpart[gw], aabs, __ATOMIC_RELAXED, __HIP_MEMORY_SCOPE_AGENT);
        #pragma unroll
        for (int b = 0; b < BATCH; ++b)
            __hip_atomic_store(&dotp[(part * BATCH + b) * HDIM + o], n[b] - 2 * d[b],
                               __ATOMIC_RELAXED, __HIP_MEMORY_SCOPE_AGENT);
    }
    // each wave drains its own sc1 stores before the block's flag goes up
    asm volatile("s_waitcnt vmcnt(0)" ::: "memory");
    __syncthreads();
    if (tid == 0)
        __hip_atomic_store(&flags[blockIdx.x], TAG, __ATOMIC_RELAXED, __HIP_MEMORY_SCOPE_AGENT);

    if (blockIdx.x != 0) return;

    // ---------------- finisher: block 0 ----------------
    __shared__ float red[256];
    #pragma unroll
    for (int i = 0; i < NBLK / 256; ++i) {
        while (__hip_atomic_load(&flags[tid * (NBLK / 256) + i],
                                 __ATOMIC_RELAXED, __HIP_MEMORY_SCOPE_AGENT) != TAG)
            __builtin_amdgcn_s_sleep(4);
    }
    __syncthreads();   // all flags observed -> all data physically in L3

    float s = 0.f;
    #pragma unroll
    for (int i = 0; i < 16; ++i)
        s += __hip_atomic_load(&wpart[tid + i * 256], __ATOMIC_RELAXED, __HIP_MEMORY_SCOPE_AGENT);
    red[tid] = s;
    __syncthreads();
    #pragma unroll
    for (int off = 128; off >= 1; off >>= 1) {
        if (tid < off) red[tid] += red[tid + off];
        __syncthreads();
    }
    float a = alpha[0];
    if (a < 1e-5f) a = 1e-5f;
    const float scale = a * red[0] * (1.0f / 1048576.0f);

    #pragma unroll
    for (int i = 0; i < 32; ++i) {
        const int idx = i * 256 + tid;          // b*1024 + oo
        const int b = idx >> 10, oo = idx & (HDIM - 1);
        int dsum = 0;
        #pragma unroll
        for (int p = 0; p < 4; ++p)
            dsum += __hip_atomic_load(&dotp[(p * BATCH + b) * HDIM + oo],
                                      __ATOMIC_RELAXED, __HIP_MEMORY_SCOPE_AGENT);
        out[idx] = tanhf(scale * (float)dsum + bias[oo]);
    }

    // reset flags for the next replay
    #pragma unroll
    for (int i = 0; i < NBLK / 256; ++i)
        __hip_atomic_store(&flags[tid * (NBLK / 256) + i], 0u,
                           __ATOMIC_RELAXED, __HIP_MEMORY_SCOPE_AGENT);
}

extern "C" void kernel_launch(void* const* d_in, const int* in_sizes, int n_in,
                              void* d_out, int out_size, void* d_ws, size_t ws_size,
                              hipStream_t stream) {
    const float* hs    = (const float*)d_in[0];
    const float* W     = (const float*)d_in[1];
    const float* bias  = (const float*)d_in[2];
    const float* alpha = (const float*)d_in[3];
    float* out = (float*)d_out;

    unsigned int* flags = (unsigned int*)d_ws;   // 1024
    float* wpart = (float*)(flags + NBLK);       // 4096
    int* dotp = (int*)(wpart + 4096);            // 32768

    k_all<<<NBLK, 256, 0, stream>>>(hs, W, bias, alpha, out, flags, wpart, dotp);
}

// Round 8
// 11.426 us; speedup vs baseline: 2.3291x; 2.3291x over previous
//
#include <hip/hip_runtime.h>
#include <math.h>

#define HDIM 1024
#define BATCH 8
#define SEQ 4096

// d_ws layout: f32 wpart[4096] | i32 dotp[4][8][1024]

__global__ __launch_bounds__(256) void k1(const float* __restrict__ hs,
                                          const float* __restrict__ W,
                                          float* __restrict__ wpart,
                                          int* __restrict__ dotp) {
    const int tid = threadIdx.x;
    const int wave = tid >> 6, lane = tid & 63;
    const int gw = blockIdx.x * 4 + wave;   // 0..4095
    const int o = gw & (HDIM - 1);          // output row
    const int part = gw >> 10;              // 0..3 quarter of the H dim
    const int h0 = part * 256 + lane * 4;

    float4 wv = *reinterpret_cast<const float4*>(W + (size_t)o * HDIM + h0);
    const float we[4] = {wv.x, wv.y, wv.z, wv.w};

    float xe[BATCH][4];
    #pragma unroll
    for (int b = 0; b < BATCH; ++b) {
        float4 xv = *reinterpret_cast<const float4*>(hs + (size_t)b * SEQ * HDIM + h0);
        xe[b][0] = xv.x; xe[b][1] = xv.y; xe[b][2] = xv.z; xe[b][3] = xv.w;
    }

    float aabs = 0.f;
    int n[BATCH], d[BATCH];
    #pragma unroll
    for (int b = 0; b < BATCH; ++b) { n[b] = 0; d[b] = 0; }

    #pragma unroll
    for (int j = 0; j < 4; ++j) {
        unsigned long long wsg = __ballot(we[j] < 0.f);
        unsigned long long wnz = __ballot(we[j] != 0.f);
        aabs += fabsf(we[j]);
        #pragma unroll
        for (int b = 0; b < BATCH; ++b) {
            unsigned long long u = wnz & __ballot(xe[b][j] != 0.f);
            unsigned long long m = (wsg ^ __ballot(xe[b][j] < 0.f)) & u;
            n[b] += __popcll(u);
            d[b] += __popcll(m);
        }
    }

    #pragma unroll
    for (int off = 32; off >= 1; off >>= 1) aabs += __shfl_down(aabs, off, 64);
    if (lane == 0) {
        wpart[gw] = aabs;
        #pragma unroll
        for (int b = 0; b < BATCH; ++b)
            dotp[(part * BATCH + b) * HDIM + o] = n[b] - 2 * d[b];
    }
}

__global__ __launch_bounds__(256) void k2(const int* __restrict__ dotp,
                                          const float* __restrict__ wpart,
                                          const float* __restrict__ bias,
                                          const float* __restrict__ alpha,
                                          float* __restrict__ out) {
    __shared__ float wsum[4];
    const int tid = threadIdx.x;
    const int wave = tid >> 6, lane = tid & 63;

    // issue the output-side loads early so they overlap the reduction
    const int idx = blockIdx.x * 256 + tid;   // b*1024 + o
    const int b = idx >> 10, o = idx & (HDIM - 1);
    int d0 = dotp[(0 * BATCH + b) * HDIM + o];
    int d1 = dotp[(1 * BATCH + b) * HDIM + o];
    int d2 = dotp[(2 * BATCH + b) * HDIM + o];
    int d3 = dotp[(3 * BATCH + b) * HDIM + o];
    float bo = bias[o];
    float a = alpha[0];

    float s = 0.f;
    #pragma unroll
    for (int i = 0; i < 16; ++i) s += wpart[tid + i * 256];
    #pragma unroll
    for (int off = 32; off >= 1; off >>= 1) s += __shfl_down(s, off, 64);
    if (lane == 0) wsum[wave] = s;
    __syncthreads();
    const float tot = wsum[0] + wsum[1] + wsum[2] + wsum[3];

    if (a < 1e-5f) a = 1e-5f;
    const float scale = a * tot * (1.0f / 1048576.0f);
    out[idx] = tanhf(scale * (float)(d0 + d1 + d2 + d3) + bo);
}

extern "C" void kernel_launch(void* const* d_in, const int* in_sizes, int n_in,
                              void* d_out, int out_size, void* d_ws, size_t ws_size,
                              hipStream_t stream) {
    const float* hs    = (const float*)d_in[0];
    const float* W     = (const float*)d_in[1];
    const float* bias  = (const float*)d_in[2];
    const float* alpha = (const float*)d_in[3];
    float* out = (float*)d_out;

    float* wpart = (float*)d_ws;                 // 4096 floats
    int* dotp = (int*)(wpart + 4096);            // 4*8*1024 ints

    k1<<<1024, 256, 0, stream>>>(hs, W, wpart, dotp);
    k2<<<(BATCH * HDIM) / 256, 256, 0, stream>>>(dotp, wpart, bias, alpha, out);
}